// Round 8
// baseline (525.450 us; speedup 1.0000x reference)
//
#include <hip/hip_runtime.h>

#define NB   32
#define NN   100000
#define NE   1000000
#define HD   64
#define AD   5
#define NL   3
#define NRL  231      // N_REL + 1
#define NTM  365
#define NOUT 228096   // 32 * 7128
#define NSEG 300000   // 3 * NN  (dst,cls) bins
#define NBLKS1 293    // ceil(NSEG/1024)

// meta packing: w0 = src | (rel<<17) ; w1 = ta | (q<<9)   (cls implicit in segment)

// bf16 helpers (hidden stored as bf16 to halve gather traffic)
__device__ __forceinline__ float bflo(unsigned u) { return __uint_as_float(u << 16); }
__device__ __forceinline__ float bfhi(unsigned u) { return __uint_as_float(u & 0xffff0000u); }
__device__ __forceinline__ unsigned packbf2(float x, float y) {
    unsigned ux = __float_as_uint(x), uy = __float_as_uint(y);
    ux = (ux + 0x7fffu + ((ux >> 16) & 1u)) >> 16;
    uy = (uy + 0x7fffu + ((uy >> 16) & 1u)) >> 16;
    return ux | (uy << 16);
}

// ---------------------------------------------------------------------------
// WT[c][k][h] = W_c[h][k], c: 0=Wf(pos) 1=Wn(zero) 2=Wp(neg)
__global__ __launch_bounds__(256) void prep_wt_kernel(
    const float* __restrict__ Wp, const float* __restrict__ Wn,
    const float* __restrict__ Wf, float* __restrict__ WT)
{
    int i = blockIdx.x * 256 + threadIdx.x;
    if (i >= 3 * 64 * 64) return;
    int c = i >> 12;
    int k = (i >> 6) & 63;
    int h = i & 63;
    const float* W = (c == 0) ? Wf : (c == 1 ? Wn : Wp);
    WT[i] = W[h * 64 + k];
}

// ---------------------------------------------------------------------------
__global__ __launch_bounds__(256) void prep_tables_kernel(
    const float* __restrict__ rela_embed,   // [3][231][64]
    const float* __restrict__ W1,           // [3][5][192]
    float* __restrict__ Trel,               // [3][231][8]
    float* __restrict__ Tq)                 // [3][231][8]
{
    int l = blockIdx.x;
    int r = threadIdx.x;
    if (r >= NRL) return;
    const float4* rrow = (const float4*)(rela_embed + ((size_t)l * NRL + r) * HD);
    const float* W1l = W1 + (size_t)l * AD * 192;
    float tr[AD] = {0,0,0,0,0}, tq[AD] = {0,0,0,0,0};
    #pragma unroll
    for (int k4 = 0; k4 < 16; ++k4) {
        float4 x = rrow[k4];
        #pragma unroll
        for (int a = 0; a < AD; ++a) {
            const float* wr = W1l + a * 192 + 64 + k4 * 4;
            const float* wq = W1l + a * 192 + 128 + k4 * 4;
            tr[a] = fmaf(x.x, wr[0], tr[a]); tr[a] = fmaf(x.y, wr[1], tr[a]);
            tr[a] = fmaf(x.z, wr[2], tr[a]); tr[a] = fmaf(x.w, wr[3], tr[a]);
            tq[a] = fmaf(x.x, wq[0], tq[a]); tq[a] = fmaf(x.y, wq[1], tq[a]);
            tq[a] = fmaf(x.z, wq[2], tq[a]); tq[a] = fmaf(x.w, wq[3], tq[a]);
        }
    }
    float* tro = Trel + ((size_t)l * NRL + r) * 8;
    float* tqo = Tq   + ((size_t)l * NRL + r) * 8;
    #pragma unroll
    for (int a = 0; a < AD; ++a) { tro[a] = tr[a]; tqo[a] = tq[a]; }
    tro[5] = tro[6] = tro[7] = 0.f;
    tqo[5] = tqo[6] = tqo[7] = 0.f;
}

// ---------------------------------------------------------------------------
// Counting sort by (dst, cls)
__global__ __launch_bounds__(256) void hist_kernel(
    const int* __restrict__ dst_idx, const int* __restrict__ rel_time,
    int* __restrict__ deg)
{
    int e = blockIdx.x * 256 + threadIdx.x;
    if (e >= NE) return;
    int rt = rel_time[e];
    int cls = (rt > 0) ? 0 : ((rt == 0) ? 1 : 2);
    atomicAdd(&deg[dst_idx[e] * 3 + cls], 1);
}

__global__ __launch_bounds__(1024) void scan1_kernel(
    const int* __restrict__ deg, int* __restrict__ tmp, int* __restrict__ bsum)
{
    __shared__ int s[1024];
    int tid = threadIdx.x;
    int i = blockIdx.x * 1024 + tid;
    int v = (i < NSEG) ? deg[i] : 0;
    s[tid] = v;
    __syncthreads();
    #pragma unroll
    for (int st = 1; st < 1024; st <<= 1) {
        int t = (tid >= st) ? s[tid - st] : 0;
        __syncthreads();
        s[tid] += t;
        __syncthreads();
    }
    if (i < NSEG) tmp[i] = s[tid];
    if (tid == 1023) bsum[blockIdx.x] = s[1023];
}

__global__ __launch_bounds__(512) void scan2_kernel(
    const int* __restrict__ bsum, int* __restrict__ bpref)
{
    __shared__ int s[512];
    int tid = threadIdx.x;
    int v = (tid < NBLKS1) ? bsum[tid] : 0;
    s[tid] = v;
    __syncthreads();
    #pragma unroll
    for (int st = 1; st < 512; st <<= 1) {
        int t = (tid >= st) ? s[tid - st] : 0;
        __syncthreads();
        s[tid] += t;
        __syncthreads();
    }
    if (tid < NBLKS1) bpref[tid] = s[tid] - v;  // exclusive
}

__global__ __launch_bounds__(256) void scan3_kernel(
    const int* __restrict__ deg, const int* __restrict__ tmp,
    const int* __restrict__ bpref, int* __restrict__ off, int* __restrict__ cursor)
{
    int i = blockIdx.x * 256 + threadIdx.x;
    if (i >= NSEG) return;
    int incl = tmp[i] + bpref[i >> 10];
    off[i + 1] = incl;
    cursor[i] = incl - deg[i];
    if (i == 0) off[0] = 0;
}

// scatter into (dst,cls)-sorted order; also computes layer-0 score
// (proj-free: sigmoid(sum_a relu(Trel0+Tq0)*W2))
__global__ __launch_bounds__(256) void sort_scatter_kernel(
    const int* __restrict__ dst_idx, const int* __restrict__ src_idx,
    const int* __restrict__ rel_idx, const int* __restrict__ rel_time,
    const int* __restrict__ batch_idx, const int* __restrict__ query_rel,
    const float* __restrict__ Trel0, const float* __restrict__ Tq0,
    const float* __restrict__ W2,
    int* __restrict__ cursor, int2* __restrict__ meta,
    float* __restrict__ score0)
{
    int e = blockIdx.x * 256 + threadIdx.x;
    if (e >= NE) return;
    int d = dst_idx[e];
    int rt = rel_time[e];
    int cls = (rt > 0) ? 0 : ((rt == 0) ? 1 : 2);
    int ta = (rt < 0) ? -rt : rt;
    int rel = rel_idx[e];
    int q = query_rel[batch_idx[e]];
    int pos = atomicAdd(&cursor[d * 3 + cls], 1);
    int2 m;
    m.x = src_idx[e] | (rel << 17);
    m.y = ta | (q << 9);
    meta[pos] = m;

    float4 t0 = *(const float4*)(Trel0 + rel * 8);
    float  t4 = Trel0[rel * 8 + 4];
    float4 u0 = *(const float4*)(Tq0 + q * 8);
    float  u4 = Tq0[q * 8 + 4];
    float z = 0.f;
    z = fmaf(fmaxf(t0.x + u0.x, 0.f), W2[0], z);
    z = fmaf(fmaxf(t0.y + u0.y, 0.f), W2[1], z);
    z = fmaf(fmaxf(t0.z + u0.z, 0.f), W2[2], z);
    z = fmaf(fmaxf(t0.w + u0.w, 0.f), W2[3], z);
    z = fmaf(fmaxf(t4   + u4,   0.f), W2[4], z);
    score0[pos] = 1.f / (1.f + __expf(-z));
}

// ---------------------------------------------------------------------------
// Standalone score for L1/L2 (64 edges/wave — R6 lesson: never fuse into the
// group-parallel reduce).
__global__ __launch_bounds__(256) void score_kernel(
    const float* __restrict__ proj,     // [NN][8]
    const float* __restrict__ Trel,
    const float* __restrict__ Tq,
    const float* __restrict__ W2,
    const int2* __restrict__ meta,
    float* __restrict__ score)
{
    int j = blockIdx.x * 256 + threadIdx.x;
    if (j >= NE) return;
    int2 mt = meta[j];
    int rel = (mt.x >> 17) & 0xFF;
    int q   = (mt.y >> 9) & 0xFF;
    int src = mt.x & 0x1FFFF;

    float4 t0 = *(const float4*)(Trel + rel * 8);
    float  t4 = Trel[rel * 8 + 4];
    float4 u0 = *(const float4*)(Tq + q * 8);
    float  u4 = Tq[q * 8 + 4];
    float4 p0 = *(const float4*)(proj + (size_t)src * 8);
    float  p4 = proj[(size_t)src * 8 + 4];
    float z = 0.f;
    z = fmaf(fmaxf(p0.x + t0.x + u0.x, 0.f), W2[0], z);
    z = fmaf(fmaxf(p0.y + t0.y + u0.y, 0.f), W2[1], z);
    z = fmaf(fmaxf(p0.z + t0.z + u0.z, 0.f), W2[2], z);
    z = fmaf(fmaxf(p0.w + t0.w + u0.w, 0.f), W2[3], z);
    z = fmaf(fmaxf(p4   + t4   + u4,   0.f), W2[4], z);
    score[j] = 1.f / (1.f + __expf(-z));
}

// ---------------------------------------------------------------------------
// One edge into a single (class-known) accumulator: 4 FMA, no selects.
template <bool HZ>
__device__ __forceinline__ void edge1(
    int2 m, float sc, int hc4,
    const ushort* __restrict__ hidden_in,
    const float* __restrict__ rela, const float* __restrict__ temb,
    float4& A)
{
    int src = m.x & 0x1FFFF, rel = (m.x >> 17) & 0xFF, ta = m.y & 511;
    float4 rv = *(const float4*)(rela + rel * HD + hc4);
    float4 tv = *(const float4*)(temb + ta * HD + hc4);
    float vx = rv.x + tv.x, vy = rv.y + tv.y;
    float vz = rv.z + tv.z, vw = rv.w + tv.w;
    if (!HZ) {
        uint2 hv = *(const uint2*)(hidden_in + (size_t)src * HD + hc4);
        vx += bflo(hv.x); vy += bfhi(hv.x);
        vz += bflo(hv.y); vw += bfhi(hv.y);
    }
    A.x = fmaf(sc, vx, A.x); A.y = fmaf(sc, vy, A.y);
    A.z = fmaf(sc, vz, A.z); A.w = fmaf(sc, vw, A.w);
}

template <bool HZ>
__device__ __forceinline__ void accum_class(
    int o0, int o1, int hc4,
    const ushort* __restrict__ hidden_in,
    const float* __restrict__ rela, const float* __restrict__ temb,
    const float* __restrict__ score, const int2* __restrict__ meta,
    float4& A)
{
    int j = o0;
    for (; j + 4 <= o1; j += 4) {
        int2 m0 = meta[j], m1 = meta[j + 1], m2 = meta[j + 2], m3 = meta[j + 3];
        float s0 = score[j], s1 = score[j + 1], s2 = score[j + 2], s3 = score[j + 3];
        edge1<HZ>(m0, s0, hc4, hidden_in, rela, temb, A);
        edge1<HZ>(m1, s1, hc4, hidden_in, rela, temb, A);
        edge1<HZ>(m2, s2, hc4, hidden_in, rela, temb, A);
        edge1<HZ>(m3, s3, hc4, hidden_in, rela, temb, A);
    }
    for (; j < o1; ++j)
        edge1<HZ>(meta[j], score[j], hc4, hidden_in, rela, temb, A);
}

// ---------------------------------------------------------------------------
// Fused segmented-reduce + transform + next-layer proj epilogue.
// Edges (dst,cls)-sorted: per class, single float4 accumulator per node.
// Class-outer structure: reduce class c -> stage LDS -> transform class c.
// Block = 4 waves = 64-node tile; group g (16 lanes) owns nodes
// nl = w*16+rr*4+g; lane covers h = hc*4..hc*4+3.
#define LPITCH 65
template <bool HZ, bool PROJ>
__global__ __launch_bounds__(256, 4) void reduce_transform_kernel(
    const ushort* __restrict__ hidden_in,   // bf16 [NN][64]
    const float* __restrict__ rela,         // layer slice [231][64] fp32
    const float* __restrict__ temb,         // [365][64] fp32
    const float* __restrict__ score,        // [E] sorted
    const int2* __restrict__ meta,          // [E] sorted
    const int*  __restrict__ off,           // [NSEG+1]
    const float* __restrict__ WT,           // [192][64]
    const float* __restrict__ W1next,       // next layer slice [5][192] (if PROJ)
    ushort* __restrict__ hidden_out,        // bf16 [NN][64]
    float* __restrict__ proj_out)           // [NN][8] (if PROJ)
{
    __shared__ float lds_t[64 * LPITCH];
    int tid  = threadIdx.x;
    int lane = tid & 63;
    int w    = __builtin_amdgcn_readfirstlane(tid >> 6);  // 0..3
    int g    = lane >> 4;                                  // 0..3
    int hc   = lane & 15;                                  // 0..15
    int hc4  = hc * 4;
    int node0 = blockIdx.x * 64;
    int h0 = w * 16;

    float acc[16];
    #pragma unroll
    for (int i = 0; i < 16; ++i) acc[i] = 0.f;

    #pragma unroll
    for (int c = 0; c < 3; ++c) {
        float4 ac[4];
        #pragma unroll
        for (int rr = 0; rr < 4; ++rr) ac[rr] = make_float4(0.f, 0.f, 0.f, 0.f);

        #pragma unroll
        for (int rr = 0; rr < 4; ++rr) {
            int nl = w * 16 + rr * 4 + g;
            int node = node0 + nl;
            if (node >= NN) continue;
            int o0 = off[3 * node + c];
            int o1 = off[3 * node + c + 1];
            accum_class<HZ>(o0, o1, hc4, hidden_in, rela, temb, score, meta, ac[rr]);
        }

        __syncthreads();   // protect previous slab's reads
        #pragma unroll
        for (int rr = 0; rr < 4; ++rr) {
            int nl = w * 16 + rr * 4 + g;
            lds_t[(hc4 + 0) * LPITCH + nl] = ac[rr].x;
            lds_t[(hc4 + 1) * LPITCH + nl] = ac[rr].y;
            lds_t[(hc4 + 2) * LPITCH + nl] = ac[rr].z;
            lds_t[(hc4 + 3) * LPITCH + nl] = ac[rr].w;
        }
        __syncthreads();
        const float* __restrict__ Wb = WT + (c * 64) * 64 + h0;
        #pragma unroll 4
        for (int k = 0; k < 64; ++k) {
            float av = lds_t[k * LPITCH + lane];
            #pragma unroll
            for (int i = 0; i < 16; ++i)
                acc[i] = fmaf(av, Wb[k * 64 + i], acc[i]);
        }
    }

    int node = node0 + lane;
    if (node < NN) {
        ushort* outp = hidden_out + (size_t)node * 64 + h0;
        unsigned up[8];
        #pragma unroll
        for (int p = 0; p < 8; ++p)
            up[p] = packbf2(fmaxf(acc[2 * p], 0.f), fmaxf(acc[2 * p + 1], 0.f));
        *(uint4*)(outp)     = make_uint4(up[0], up[1], up[2], up[3]);
        *(uint4*)(outp + 8) = make_uint4(up[4], up[5], up[6], up[7]);
    }

    // --- epilogue: proj for NEXT layer from fp32 acc (exact) ---
    if (PROJ) {
        float pa[AD];
        #pragma unroll
        for (int aa = 0; aa < AD; ++aa) pa[aa] = 0.f;
        #pragma unroll
        for (int i = 0; i < 16; ++i) {
            float hv = fmaxf(acc[i], 0.f);
            #pragma unroll
            for (int aa = 0; aa < AD; ++aa)
                pa[aa] = fmaf(hv, W1next[aa * 192 + h0 + i], pa[aa]);
        }
        __syncthreads();
        float* lds2 = lds_t;   // reuse as [4][64][5]
        #pragma unroll
        for (int aa = 0; aa < AD; ++aa)
            lds2[(w * 64 + lane) * AD + aa] = pa[aa];
        __syncthreads();
        for (int idx = tid; idx < 64 * 8; idx += 256) {
            int nd = idx >> 3, aa = idx & 7;
            if (node0 + nd >= NN) break;
            float v = 0.f;
            if (aa < AD) {
                #pragma unroll
                for (int w4 = 0; w4 < 4; ++w4)
                    v += lds2[(w4 * 64 + nd) * AD + aa];
            }
            proj_out[(size_t)(node0 + nd) * 8 + aa] = v;
        }
    }
}

// ---------------------------------------------------------------------------
__global__ __launch_bounds__(256) void out_kernel(
    const ushort* __restrict__ hidden,   // bf16 [NN][64]
    const float* __restrict__ Wc,
    const float* __restrict__ bc,
    float* __restrict__ out)
{
    int i = blockIdx.x * 256 + threadIdx.x;
    if (i >= NOUT) return;
    float r = 0.f;
    if (i < NN) {
        const uint4* h4 = (const uint4*)(hidden + (size_t)i * 64);
        float acc = 0.f;
        #pragma unroll
        for (int q = 0; q < 8; ++q) {
            uint4 hv = h4[q];
            const float* wq = Wc + q * 8;
            acc = fmaf(bflo(hv.x), wq[0], acc);
            acc = fmaf(bfhi(hv.x), wq[1], acc);
            acc = fmaf(bflo(hv.y), wq[2], acc);
            acc = fmaf(bfhi(hv.y), wq[3], acc);
            acc = fmaf(bflo(hv.z), wq[4], acc);
            acc = fmaf(bfhi(hv.z), wq[5], acc);
            acc = fmaf(bflo(hv.w), wq[6], acc);
            acc = fmaf(bfhi(hv.w), wq[7], acc);
        }
        r = acc + bc[0];
    }
    out[i] = r;
}

// ---------------------------------------------------------------------------
extern "C" void kernel_launch(void* const* d_in, const int* in_sizes, int n_in,
                              void* d_out, int out_size, void* d_ws, size_t ws_size,
                              hipStream_t stream)
{
    const int*   batch_idx  = (const int*)d_in[0];
    const int*   src_idx    = (const int*)d_in[1];
    const int*   dst_idx    = (const int*)d_in[2];
    const int*   rel_idx    = (const int*)d_in[3];
    const int*   rel_time   = (const int*)d_in[4];
    const int*   query_rel  = (const int*)d_in[5];
    const float* rela_embed = (const float*)d_in[8];   // [3][231][64]
    const float* time_embed = (const float*)d_in[9];   // [365][64]
    const float* Wp         = (const float*)d_in[10];
    const float* Wn         = (const float*)d_in[11];
    const float* Wf         = (const float*)d_in[12];
    const float* W1         = (const float*)d_in[13];  // [3][5][192]
    const float* W2         = (const float*)d_in[14];  // [3][1][5]
    const float* Wc         = (const float*)d_in[15];  // [64]
    const float* bc         = (const float*)d_in[16];  // [1]
    float* out = (float*)d_out;

    char* ws = (char*)d_ws;
    ushort* hid0  = (ushort*)(ws + 0);           // 12.8 MB bf16
    ushort* hid1  = (ushort*)(ws + 12800000);    // 12.8 MB bf16
    float* projA  = (float*)(ws + 25600000);     //  3.2 MB
    float* projB  = (float*)(ws + 28800000);     //  3.2 MB
    float* score  = (float*)(ws + 32000000);     //  4.0 MB
    float* WT     = (float*)(ws + 36000000);     //  48 KB
    float* Trel   = (float*)(ws + 36100000);     //  ~22 KB
    float* Tq     = (float*)(ws + 36130000);     //  ~22 KB
    int*   off    = (int*)  (ws + 36160000);     //  1.2 MB (NSEG+1)
    int2*  meta   = (int2*) (ws + 37400000);     //  8.0 MB
    int*   deg    = (int*)  (ws + 45400000);     //  1.2 MB
    int*   tmp    = (int*)  (ws + 46600000);     //  1.2 MB
    int*   cursor = (int*)  (ws + 47800000);     //  1.2 MB
    int*   bsum   = (int*)  (ws + 49000000);     //  ~1.2 KB
    int*   bpref  = (int*)  (ws + 49010000);     //  ~1.2 KB

    prep_wt_kernel<<<48, 256, 0, stream>>>(Wp, Wn, Wf, WT);
    prep_tables_kernel<<<NL, 256, 0, stream>>>(rela_embed, W1, Trel, Tq);

    // --- counting sort by (dst, cls); layer-0 score computed in scatter ---
    hipMemsetAsync(deg, 0, NSEG * sizeof(int), stream);
    hist_kernel<<<(NE + 255) / 256, 256, 0, stream>>>(dst_idx, rel_time, deg);
    scan1_kernel<<<NBLKS1, 1024, 0, stream>>>(deg, tmp, bsum);
    scan2_kernel<<<1, 512, 0, stream>>>(bsum, bpref);
    scan3_kernel<<<(NSEG + 255) / 256, 256, 0, stream>>>(deg, tmp, bpref, off, cursor);
    sort_scatter_kernel<<<(NE + 255) / 256, 256, 0, stream>>>(
        dst_idx, src_idx, rel_idx, rel_time, batch_idx, query_rel,
        Trel, Tq, W2, cursor, meta, score);

    // --- layers: L0 -> hid0/projA ; L1 hid0,projA -> hid1/projB ;
    //             L2 hid1,projB -> hid0 ---
    int grid = (NN + 63) / 64;
    int sgrid = (NE + 255) / 256;
    {
        reduce_transform_kernel<true, true><<<grid, 256, 0, stream>>>(
            hid1, rela_embed, time_embed, score, meta, off,
            WT, W1 + (size_t)1 * AD * 192, hid0, projA);
    }
    {
        const float* rela = rela_embed + (size_t)1 * NRL * HD;
        score_kernel<<<sgrid, 256, 0, stream>>>(
            projA, Trel + (size_t)1 * NRL * 8, Tq + (size_t)1 * NRL * 8,
            W2 + 1 * AD, meta, score);
        reduce_transform_kernel<false, true><<<grid, 256, 0, stream>>>(
            hid0, rela, time_embed, score, meta, off,
            WT, W1 + (size_t)2 * AD * 192, hid1, projB);
    }
    {
        const float* rela = rela_embed + (size_t)2 * NRL * HD;
        score_kernel<<<sgrid, 256, 0, stream>>>(
            projB, Trel + (size_t)2 * NRL * 8, Tq + (size_t)2 * NRL * 8,
            W2 + 2 * AD, meta, score);
        reduce_transform_kernel<false, false><<<grid, 256, 0, stream>>>(
            hid1, rela, time_embed, score, meta, off,
            WT, nullptr, hid0, nullptr);
    }

    out_kernel<<<(NOUT + 255) / 256, 256, 0, stream>>>(hid0, Wc, bc, out);
}

// Round 9
// 466.680 us; speedup vs baseline: 1.1259x; 1.1259x over previous
//
#include <hip/hip_runtime.h>

#define NB   32
#define NN   100000
#define NE   1000000
#define HD   64
#define AD   5
#define NL   3
#define NRL  231      // N_REL + 1
#define NTM  365
#define NOUT 228096   // 32 * 7128
#define NBLK1 391     // ceil(NN/256)

// meta packing: w0 = src | (rel<<17) | (cls<<25) ; w1 = ta | (q<<9)

// bf16 helpers (hidden stored as bf16 to halve gather traffic)
__device__ __forceinline__ float bflo(unsigned u) { return __uint_as_float(u << 16); }
__device__ __forceinline__ float bfhi(unsigned u) { return __uint_as_float(u & 0xffff0000u); }
__device__ __forceinline__ unsigned packbf2(float x, float y) {
    unsigned ux = __float_as_uint(x), uy = __float_as_uint(y);
    ux = (ux + 0x7fffu + ((ux >> 16) & 1u)) >> 16;
    uy = (uy + 0x7fffu + ((uy >> 16) & 1u)) >> 16;
    return ux | (uy << 16);
}

// ---------------------------------------------------------------------------
// WT[c][k][h] = W_c[h][k], c: 0=Wf(pos) 1=Wn(zero) 2=Wp(neg)
__global__ __launch_bounds__(256) void prep_wt_kernel(
    const float* __restrict__ Wp, const float* __restrict__ Wn,
    const float* __restrict__ Wf, float* __restrict__ WT)
{
    int i = blockIdx.x * 256 + threadIdx.x;
    if (i >= 3 * 64 * 64) return;
    int c = i >> 12;
    int k = (i >> 6) & 63;
    int h = i & 63;
    const float* W = (c == 0) ? Wf : (c == 1 ? Wn : Wp);
    WT[i] = W[h * 64 + k];
}

// ---------------------------------------------------------------------------
__global__ __launch_bounds__(256) void prep_tables_kernel(
    const float* __restrict__ rela_embed,   // [3][231][64]
    const float* __restrict__ W1,           // [3][5][192]
    float* __restrict__ Trel,               // [3][231][8]
    float* __restrict__ Tq)                 // [3][231][8]
{
    int l = blockIdx.x;
    int r = threadIdx.x;
    if (r >= NRL) return;
    const float4* rrow = (const float4*)(rela_embed + ((size_t)l * NRL + r) * HD);
    const float* W1l = W1 + (size_t)l * AD * 192;
    float tr[AD] = {0,0,0,0,0}, tq[AD] = {0,0,0,0,0};
    #pragma unroll
    for (int k4 = 0; k4 < 16; ++k4) {
        float4 x = rrow[k4];
        #pragma unroll
        for (int a = 0; a < AD; ++a) {
            const float* wr = W1l + a * 192 + 64 + k4 * 4;
            const float* wq = W1l + a * 192 + 128 + k4 * 4;
            tr[a] = fmaf(x.x, wr[0], tr[a]); tr[a] = fmaf(x.y, wr[1], tr[a]);
            tr[a] = fmaf(x.z, wr[2], tr[a]); tr[a] = fmaf(x.w, wr[3], tr[a]);
            tq[a] = fmaf(x.x, wq[0], tq[a]); tq[a] = fmaf(x.y, wq[1], tq[a]);
            tq[a] = fmaf(x.z, wq[2], tq[a]); tq[a] = fmaf(x.w, wq[3], tq[a]);
        }
    }
    float* tro = Trel + ((size_t)l * NRL + r) * 8;
    float* tqo = Tq   + ((size_t)l * NRL + r) * 8;
    #pragma unroll
    for (int a = 0; a < AD; ++a) { tro[a] = tr[a]; tqo[a] = tq[a]; }
    tro[5] = tro[6] = tro[7] = 0.f;
    tqo[5] = tqo[6] = tqo[7] = 0.f;
}

// ---------------------------------------------------------------------------
// Counting sort by dst (dst-only: long segments keep MLP alive — R8 lesson)
__global__ __launch_bounds__(256) void hist_kernel(
    const int* __restrict__ dst_idx, int* __restrict__ deg)
{
    int e = blockIdx.x * 256 + threadIdx.x;
    if (e < NE) atomicAdd(&deg[dst_idx[e]], 1);
}

__global__ __launch_bounds__(256) void scan1_kernel(
    const int* __restrict__ deg, int* __restrict__ tmp, int* __restrict__ bsum)
{
    __shared__ int s[256];
    int tid = threadIdx.x;
    int i = blockIdx.x * 256 + tid;
    int v = (i < NN) ? deg[i] : 0;
    s[tid] = v;
    __syncthreads();
    #pragma unroll
    for (int st = 1; st < 256; st <<= 1) {
        int t = (tid >= st) ? s[tid - st] : 0;
        __syncthreads();
        s[tid] += t;
        __syncthreads();
    }
    if (i < NN) tmp[i] = s[tid];
    if (tid == 255) bsum[blockIdx.x] = s[255];
}

__global__ __launch_bounds__(512) void scan2_kernel(
    const int* __restrict__ bsum, int* __restrict__ bpref)
{
    __shared__ int s[512];
    int tid = threadIdx.x;
    int v = (tid < NBLK1) ? bsum[tid] : 0;
    s[tid] = v;
    __syncthreads();
    #pragma unroll
    for (int st = 1; st < 512; st <<= 1) {
        int t = (tid >= st) ? s[tid - st] : 0;
        __syncthreads();
        s[tid] += t;
        __syncthreads();
    }
    if (tid < NBLK1) bpref[tid] = s[tid] - v;  // exclusive
}

__global__ __launch_bounds__(256) void scan3_kernel(
    const int* __restrict__ deg, const int* __restrict__ tmp,
    const int* __restrict__ bpref, int* __restrict__ off, int* __restrict__ cursor)
{
    int i = blockIdx.x * 256 + threadIdx.x;
    if (i >= NN) return;
    int incl = tmp[i] + bpref[i >> 8];
    off[i + 1] = incl;
    cursor[i] = incl - deg[i];
    if (i == 0) off[0] = 0;
}

// scatter into dst-sorted order; also computes layer-0 score
// (proj-free: sigmoid(sum_a relu(Trel0+Tq0)*W2))
__global__ __launch_bounds__(256) void sort_scatter_kernel(
    const int* __restrict__ dst_idx, const int* __restrict__ src_idx,
    const int* __restrict__ rel_idx, const int* __restrict__ rel_time,
    const int* __restrict__ batch_idx, const int* __restrict__ query_rel,
    const float* __restrict__ Trel0, const float* __restrict__ Tq0,
    const float* __restrict__ W2,
    int* __restrict__ cursor, int2* __restrict__ meta,
    float* __restrict__ score0)
{
    int e = blockIdx.x * 256 + threadIdx.x;
    if (e >= NE) return;
    int d = dst_idx[e];
    int rt = rel_time[e];
    int cls = (rt > 0) ? 0 : ((rt == 0) ? 1 : 2);
    int ta = (rt < 0) ? -rt : rt;
    int rel = rel_idx[e];
    int q = query_rel[batch_idx[e]];
    int pos = atomicAdd(&cursor[d], 1);
    int2 m;
    m.x = src_idx[e] | (rel << 17) | (cls << 25);
    m.y = ta | (q << 9);
    meta[pos] = m;

    float4 t0 = *(const float4*)(Trel0 + rel * 8);
    float  t4 = Trel0[rel * 8 + 4];
    float4 u0 = *(const float4*)(Tq0 + q * 8);
    float  u4 = Tq0[q * 8 + 4];
    float z = 0.f;
    z = fmaf(fmaxf(t0.x + u0.x, 0.f), W2[0], z);
    z = fmaf(fmaxf(t0.y + u0.y, 0.f), W2[1], z);
    z = fmaf(fmaxf(t0.z + u0.z, 0.f), W2[2], z);
    z = fmaf(fmaxf(t0.w + u0.w, 0.f), W2[3], z);
    z = fmaf(fmaxf(t4   + u4,   0.f), W2[4], z);
    score0[pos] = 1.f / (1.f + __expf(-z));
}

// ---------------------------------------------------------------------------
// Standalone score for L1/L2 (64 edges/wave — R6 lesson).
__global__ __launch_bounds__(256) void score_kernel(
    const float* __restrict__ proj,     // [NN][8]
    const float* __restrict__ Trel,
    const float* __restrict__ Tq,
    const float* __restrict__ W2,
    const int2* __restrict__ meta,
    float* __restrict__ score)
{
    int j = blockIdx.x * 256 + threadIdx.x;
    if (j >= NE) return;
    int2 mt = meta[j];
    int rel = (mt.x >> 17) & 0xFF;
    int q   = (mt.y >> 9) & 0xFF;
    int src = mt.x & 0x1FFFF;

    float4 t0 = *(const float4*)(Trel + rel * 8);
    float  t4 = Trel[rel * 8 + 4];
    float4 u0 = *(const float4*)(Tq + q * 8);
    float  u4 = Tq[q * 8 + 4];
    float4 p0 = *(const float4*)(proj + (size_t)src * 8);
    float  p4 = proj[(size_t)src * 8 + 4];
    float z = 0.f;
    z = fmaf(fmaxf(p0.x + t0.x + u0.x, 0.f), W2[0], z);
    z = fmaf(fmaxf(p0.y + t0.y + u0.y, 0.f), W2[1], z);
    z = fmaf(fmaxf(p0.z + t0.z + u0.z, 0.f), W2[2], z);
    z = fmaf(fmaxf(p0.w + t0.w + u0.w, 0.f), W2[3], z);
    z = fmaf(fmaxf(p4   + t4   + u4,   0.f), W2[4], z);
    score[j] = 1.f / (1.f + __expf(-z));
}

// ---------------------------------------------------------------------------
// One edge, 8-lane group (lane covers h = hc*8..hc*8+7).
// A[6] = [cls0 h0..3, cls0 h4..7, cls1 lo, cls1 hi, cls2 lo, cls2 hi]
template <bool HZ>
__device__ __forceinline__ void edge1(
    int2 m, float sc, int hc8,
    const ushort* __restrict__ hidden_in,
    const float* __restrict__ rela, const float* __restrict__ temb,
    float4* __restrict__ A)
{
    int src = m.x & 0x1FFFF, rel = (m.x >> 17) & 0xFF;
    int cl  = (m.x >> 25) & 3, ta = m.y & 511;
    const float* rp = rela + rel * HD + hc8;
    const float* tp = temb + ta * HD + hc8;
    float4 rv0 = *(const float4*)rp;
    float4 rv1 = *(const float4*)(rp + 4);
    float4 tv0 = *(const float4*)tp;
    float4 tv1 = *(const float4*)(tp + 4);
    float4 v0, v1;
    v0.x = rv0.x + tv0.x; v0.y = rv0.y + tv0.y;
    v0.z = rv0.z + tv0.z; v0.w = rv0.w + tv0.w;
    v1.x = rv1.x + tv1.x; v1.y = rv1.y + tv1.y;
    v1.z = rv1.z + tv1.z; v1.w = rv1.w + tv1.w;
    if (!HZ) {
        uint4 hv = *(const uint4*)(hidden_in + (size_t)src * HD + hc8);
        v0.x += bflo(hv.x); v0.y += bfhi(hv.x);
        v0.z += bflo(hv.y); v0.w += bfhi(hv.y);
        v1.x += bflo(hv.z); v1.y += bfhi(hv.z);
        v1.z += bflo(hv.w); v1.w += bfhi(hv.w);
    }
    float sA = (cl == 0) ? sc : 0.f;
    float sB = (cl == 1) ? sc : 0.f;
    float sC = (cl == 2) ? sc : 0.f;
    A[0].x = fmaf(sA, v0.x, A[0].x); A[0].y = fmaf(sA, v0.y, A[0].y);
    A[0].z = fmaf(sA, v0.z, A[0].z); A[0].w = fmaf(sA, v0.w, A[0].w);
    A[1].x = fmaf(sA, v1.x, A[1].x); A[1].y = fmaf(sA, v1.y, A[1].y);
    A[1].z = fmaf(sA, v1.z, A[1].z); A[1].w = fmaf(sA, v1.w, A[1].w);
    A[2].x = fmaf(sB, v0.x, A[2].x); A[2].y = fmaf(sB, v0.y, A[2].y);
    A[2].z = fmaf(sB, v0.z, A[2].z); A[2].w = fmaf(sB, v0.w, A[2].w);
    A[3].x = fmaf(sB, v1.x, A[3].x); A[3].y = fmaf(sB, v1.y, A[3].y);
    A[3].z = fmaf(sB, v1.z, A[3].z); A[3].w = fmaf(sB, v1.w, A[3].w);
    A[4].x = fmaf(sC, v0.x, A[4].x); A[4].y = fmaf(sC, v0.y, A[4].y);
    A[4].z = fmaf(sC, v0.z, A[4].z); A[4].w = fmaf(sC, v0.w, A[4].w);
    A[5].x = fmaf(sC, v1.x, A[5].x); A[5].y = fmaf(sC, v1.y, A[5].y);
    A[5].z = fmaf(sC, v1.z, A[5].z); A[5].w = fmaf(sC, v1.w, A[5].w);
}

// ---------------------------------------------------------------------------
// Fused segmented-reduce + transform + next-layer proj epilogue.
// 8-lane groups: wave = 8 groups -> 8 edges in flight (x2 unroll -> 16).
// Block = 4 waves = 64-node tile; wave w owns nodes w*16..w*16+15;
// group g (lane>>3) owns nodes nl = w*16 + rr*8 + g, rr=0..1.
// Class-slab transform (16.6 KB LDS) unchanged.
#define LPITCH 65
template <bool HZ, bool PROJ>
__global__ __launch_bounds__(256, 4) void reduce_transform_kernel(
    const ushort* __restrict__ hidden_in,   // bf16 [NN][64]
    const float* __restrict__ rela,         // layer slice [231][64] fp32
    const float* __restrict__ temb,         // [365][64] fp32
    const float* __restrict__ score,        // [E] sorted
    const int2* __restrict__ meta,          // [E] sorted
    const int*  __restrict__ off,           // [NN+1]
    const float* __restrict__ WT,           // [192][64]
    const float* __restrict__ W1next,       // next layer slice [5][192] (if PROJ)
    ushort* __restrict__ hidden_out,        // bf16 [NN][64]
    float* __restrict__ proj_out)           // [NN][8] (if PROJ)
{
    __shared__ float lds_t[64 * LPITCH];
    int tid  = threadIdx.x;
    int lane = tid & 63;
    int w    = __builtin_amdgcn_readfirstlane(tid >> 6);  // 0..3
    int g    = lane >> 3;                                  // 0..7
    int hc   = lane & 7;                                   // 0..7
    int hc8  = hc * 8;
    int node0 = blockIdx.x * 64;
    int h0 = w * 16;

    float4 a[2][6];
    #pragma unroll
    for (int rr = 0; rr < 2; ++rr)
        #pragma unroll
        for (int c = 0; c < 6; ++c)
            a[rr][c] = make_float4(0.f, 0.f, 0.f, 0.f);

    #pragma unroll
    for (int rr = 0; rr < 2; ++rr) {
        int nl = w * 16 + rr * 8 + g;
        int node = node0 + nl;
        if (node >= NN) continue;
        int o0 = off[node];
        int o1 = off[node + 1];
        int j = o0;
        for (; j + 2 <= o1; j += 2) {
            int2 m0 = meta[j], m1 = meta[j + 1];
            float s0 = score[j], s1 = score[j + 1];
            edge1<HZ>(m0, s0, hc8, hidden_in, rela, temb, a[rr]);
            edge1<HZ>(m1, s1, hc8, hidden_in, rela, temb, a[rr]);
        }
        if (j < o1)
            edge1<HZ>(meta[j], score[j], hc8, hidden_in, rela, temb, a[rr]);
    }

    // --- transform, one class slab at a time ---
    float acc[16];
    #pragma unroll
    for (int i = 0; i < 16; ++i) acc[i] = 0.f;

    #pragma unroll
    for (int c = 0; c < 3; ++c) {
        __syncthreads();   // protect previous slab's reads
        #pragma unroll
        for (int rr = 0; rr < 2; ++rr) {
            int nl = w * 16 + rr * 8 + g;
            float4 lo = a[rr][2 * c];
            float4 hi = a[rr][2 * c + 1];
            lds_t[(hc8 + 0) * LPITCH + nl] = lo.x;
            lds_t[(hc8 + 1) * LPITCH + nl] = lo.y;
            lds_t[(hc8 + 2) * LPITCH + nl] = lo.z;
            lds_t[(hc8 + 3) * LPITCH + nl] = lo.w;
            lds_t[(hc8 + 4) * LPITCH + nl] = hi.x;
            lds_t[(hc8 + 5) * LPITCH + nl] = hi.y;
            lds_t[(hc8 + 6) * LPITCH + nl] = hi.z;
            lds_t[(hc8 + 7) * LPITCH + nl] = hi.w;
        }
        __syncthreads();
        const float* __restrict__ Wb = WT + (c * 64) * 64 + h0;
        #pragma unroll 4
        for (int k = 0; k < 64; ++k) {
            float av = lds_t[k * LPITCH + lane];
            #pragma unroll
            for (int i = 0; i < 16; ++i)
                acc[i] = fmaf(av, Wb[k * 64 + i], acc[i]);
        }
    }

    int node = node0 + lane;
    if (node < NN) {
        ushort* outp = hidden_out + (size_t)node * 64 + h0;
        unsigned up[8];
        #pragma unroll
        for (int p = 0; p < 8; ++p)
            up[p] = packbf2(fmaxf(acc[2 * p], 0.f), fmaxf(acc[2 * p + 1], 0.f));
        *(uint4*)(outp)     = make_uint4(up[0], up[1], up[2], up[3]);
        *(uint4*)(outp + 8) = make_uint4(up[4], up[5], up[6], up[7]);
    }

    // --- epilogue: proj for NEXT layer from fp32 acc (exact) ---
    if (PROJ) {
        float pa[AD];
        #pragma unroll
        for (int aa = 0; aa < AD; ++aa) pa[aa] = 0.f;
        #pragma unroll
        for (int i = 0; i < 16; ++i) {
            float hv = fmaxf(acc[i], 0.f);
            #pragma unroll
            for (int aa = 0; aa < AD; ++aa)
                pa[aa] = fmaf(hv, W1next[aa * 192 + h0 + i], pa[aa]);
        }
        __syncthreads();
        float* lds2 = lds_t;   // reuse as [4][64][5]
        #pragma unroll
        for (int aa = 0; aa < AD; ++aa)
            lds2[(w * 64 + lane) * AD + aa] = pa[aa];
        __syncthreads();
        for (int idx = tid; idx < 64 * 8; idx += 256) {
            int nd = idx >> 3, aa = idx & 7;
            if (node0 + nd >= NN) break;
            float v = 0.f;
            if (aa < AD) {
                #pragma unroll
                for (int w4 = 0; w4 < 4; ++w4)
                    v += lds2[(w4 * 64 + nd) * AD + aa];
            }
            proj_out[(size_t)(node0 + nd) * 8 + aa] = v;
        }
    }
}

// ---------------------------------------------------------------------------
__global__ __launch_bounds__(256) void out_kernel(
    const ushort* __restrict__ hidden,   // bf16 [NN][64]
    const float* __restrict__ Wc,
    const float* __restrict__ bc,
    float* __restrict__ out)
{
    int i = blockIdx.x * 256 + threadIdx.x;
    if (i >= NOUT) return;
    float r = 0.f;
    if (i < NN) {
        const uint4* h4 = (const uint4*)(hidden + (size_t)i * 64);
        float acc = 0.f;
        #pragma unroll
        for (int q = 0; q < 8; ++q) {
            uint4 hv = h4[q];
            const float* wq = Wc + q * 8;
            acc = fmaf(bflo(hv.x), wq[0], acc);
            acc = fmaf(bfhi(hv.x), wq[1], acc);
            acc = fmaf(bflo(hv.y), wq[2], acc);
            acc = fmaf(bfhi(hv.y), wq[3], acc);
            acc = fmaf(bflo(hv.z), wq[4], acc);
            acc = fmaf(bfhi(hv.z), wq[5], acc);
            acc = fmaf(bflo(hv.w), wq[6], acc);
            acc = fmaf(bfhi(hv.w), wq[7], acc);
        }
        r = acc + bc[0];
    }
    out[i] = r;
}

// ---------------------------------------------------------------------------
extern "C" void kernel_launch(void* const* d_in, const int* in_sizes, int n_in,
                              void* d_out, int out_size, void* d_ws, size_t ws_size,
                              hipStream_t stream)
{
    const int*   batch_idx  = (const int*)d_in[0];
    const int*   src_idx    = (const int*)d_in[1];
    const int*   dst_idx    = (const int*)d_in[2];
    const int*   rel_idx    = (const int*)d_in[3];
    const int*   rel_time   = (const int*)d_in[4];
    const int*   query_rel  = (const int*)d_in[5];
    const float* rela_embed = (const float*)d_in[8];   // [3][231][64]
    const float* time_embed = (const float*)d_in[9];   // [365][64]
    const float* Wp         = (const float*)d_in[10];
    const float* Wn         = (const float*)d_in[11];
    const float* Wf         = (const float*)d_in[12];
    const float* W1         = (const float*)d_in[13];  // [3][5][192]
    const float* W2         = (const float*)d_in[14];  // [3][1][5]
    const float* Wc         = (const float*)d_in[15];  // [64]
    const float* bc         = (const float*)d_in[16];  // [1]
    float* out = (float*)d_out;

    char* ws = (char*)d_ws;
    ushort* hid0  = (ushort*)(ws + 0);           // 12.8 MB bf16
    ushort* hid1  = (ushort*)(ws + 12800000);    // 12.8 MB bf16
    float* projA  = (float*)(ws + 25600000);     //  3.2 MB
    float* projB  = (float*)(ws + 28800000);     //  3.2 MB
    float* score  = (float*)(ws + 32000000);     //  4.0 MB
    float* WT     = (float*)(ws + 36000000);     //  48 KB
    float* Trel   = (float*)(ws + 36100000);     //  ~22 KB
    float* Tq     = (float*)(ws + 36130000);     //  ~22 KB
    int*   off    = (int*)  (ws + 36160000);     // 400 KB (NN+1)
    int2*  meta   = (int2*) (ws + 37400000);     //  8.0 MB
    int*   deg    = (int*)  (ws + 45400000);     // 400 KB
    int*   tmp    = (int*)  (ws + 46600000);     // 400 KB
    int*   cursor = (int*)  (ws + 47800000);     // 400 KB
    int*   bsum   = (int*)  (ws + 49000000);     //  ~2 KB
    int*   bpref  = (int*)  (ws + 49010000);     //  ~2 KB

    prep_wt_kernel<<<48, 256, 0, stream>>>(Wp, Wn, Wf, WT);
    prep_tables_kernel<<<NL, 256, 0, stream>>>(rela_embed, W1, Trel, Tq);

    // --- counting sort by dst; layer-0 score computed in scatter ---
    hipMemsetAsync(deg, 0, NN * sizeof(int), stream);
    hist_kernel<<<(NE + 255) / 256, 256, 0, stream>>>(dst_idx, deg);
    scan1_kernel<<<NBLK1, 256, 0, stream>>>(deg, tmp, bsum);
    scan2_kernel<<<1, 512, 0, stream>>>(bsum, bpref);
    scan3_kernel<<<NBLK1, 256, 0, stream>>>(deg, tmp, bpref, off, cursor);
    sort_scatter_kernel<<<(NE + 255) / 256, 256, 0, stream>>>(
        dst_idx, src_idx, rel_idx, rel_time, batch_idx, query_rel,
        Trel, Tq, W2, cursor, meta, score);

    // --- layers: L0 -> hid0/projA ; L1 hid0,projA -> hid1/projB ;
    //             L2 hid1,projB -> hid0 ---
    int grid = (NN + 63) / 64;
    int sgrid = (NE + 255) / 256;
    {
        reduce_transform_kernel<true, true><<<grid, 256, 0, stream>>>(
            hid1, rela_embed, time_embed, score, meta, off,
            WT, W1 + (size_t)1 * AD * 192, hid0, projA);
    }
    {
        const float* rela = rela_embed + (size_t)1 * NRL * HD;
        score_kernel<<<sgrid, 256, 0, stream>>>(
            projA, Trel + (size_t)1 * NRL * 8, Tq + (size_t)1 * NRL * 8,
            W2 + 1 * AD, meta, score);
        reduce_transform_kernel<false, true><<<grid, 256, 0, stream>>>(
            hid0, rela, time_embed, score, meta, off,
            WT, W1 + (size_t)2 * AD * 192, hid1, projB);
    }
    {
        const float* rela = rela_embed + (size_t)2 * NRL * HD;
        score_kernel<<<sgrid, 256, 0, stream>>>(
            projB, Trel + (size_t)2 * NRL * 8, Tq + (size_t)2 * NRL * 8,
            W2 + 2 * AD, meta, score);
        reduce_transform_kernel<false, false><<<grid, 256, 0, stream>>>(
            hid1, rela, time_embed, score, meta, off,
            WT, nullptr, hid0, nullptr);
    }

    out_kernel<<<(NOUT + 255) / 256, 256, 0, stream>>>(hid0, Wc, bc, out);
}